// Round 2
// baseline (6139.141 us; speedup 1.0000x reference)
//
#include <hip/hip_runtime.h>
#include <hip/hip_bf16.h>
#include <math.h>

// ---------------------------------------------------------------------------
// DecoderTARDIS forward, fp32. Structure:
//   prologue: pack Wcat/Wicat (padded to 1344 cols), addrW (+transpose), init,
//             one 4096x512x1344 GEMM for icat.
//   per step: prep_gemm (h@Wcat split-K partials, 336 blocks)
//             chain_kernel (per-batch block: everything else, incl. in-kernel
//             threefry gumbel and next-step u2w). 2 launches/step.
// Sparse-memory insight: mem[:, :, A:] has at most one written row per batch
// per step -> maintain valHist/valWHist + lastWriter instead of dense mem,
// and logits = coalesced pass over static addrW^T + correction pass over the
// <=32 written slots.
// ---------------------------------------------------------------------------

static constexpr int LL    = 32;
static constexpr int BB    = 128;
static constexpr int ID    = 512;
static constexpr int HD    = 1024;
static constexpr int NS    = 512;
static constexpr int AA    = 128;
static constexpr int CCd   = 128;
static constexpr int AC    = 256;
static constexpr int WC    = 1344;   // packed cols, padded from 1286 to /64
static constexpr int COL_W0  = 1024;
static constexpr int COL_G0  = 1280;
static constexpr int COL_AB0 = 1283;
static constexpr int COL_TAU = 1285;

// ------------------------------ threefry -----------------------------------
__device__ __forceinline__ uint32_t rotl32(uint32_t x, uint32_t r) {
  return (x << r) | (x >> (32u - r));
}

__device__ __forceinline__ void threefry2x32(uint32_t k0, uint32_t k1,
                                             uint32_t x0, uint32_t x1,
                                             uint32_t& o0, uint32_t& o1) {
  uint32_t ks0 = k0, ks1 = k1, ks2 = 0x1BD11BDAu ^ k0 ^ k1;
  x0 += ks0; x1 += ks1;
#define TFR(r) { x0 += x1; x1 = rotl32(x1, r); x1 ^= x0; }
  TFR(13u) TFR(15u) TFR(26u) TFR(6u)   x0 += ks1; x1 += ks2 + 1u;
  TFR(17u) TFR(29u) TFR(16u) TFR(24u)  x0 += ks2; x1 += ks0 + 2u;
  TFR(13u) TFR(15u) TFR(26u) TFR(6u)   x0 += ks0; x1 += ks1 + 3u;
  TFR(17u) TFR(29u) TFR(16u) TFR(24u)  x0 += ks1; x1 += ks2 + 4u;
  TFR(13u) TFR(15u) TFR(26u) TFR(6u)   x0 += ks2; x1 += ks0 + 5u;
#undef TFR
  o0 = x0; o1 = x1;
}

__device__ __forceinline__ float bits_to_gumbel(uint32_t bits) {
  uint32_t v = (bits >> 9) | 0x3F800000u;
  float f = __uint_as_float(v) - 1.0f;
  if (f <= 0.0f) f = 1.17549435e-38f;
  return -logf(-logf(f));
}

// ------------------------------ prologue -----------------------------------
__global__ void pack_wcat(const float* __restrict__ Wh2c, const float* __restrict__ Wh2w,
                          const float* __restrict__ Wh2g, const float* __restrict__ Wh2ab,
                          const float* __restrict__ Wh2tau, float* __restrict__ Wcat) {
  int idx = blockIdx.x * blockDim.x + threadIdx.x;
  if (idx >= HD * WC) return;
  int k = idx / WC, c = idx % WC;
  float v = 0.0f;
  if (c < 1024)       v = Wh2c[(size_t)k * HD + c];
  else if (c < 1280)  v = Wh2w[(size_t)k * AC + (c - 1024)];
  else if (c < 1283)  v = Wh2g[k * 3 + (c - 1280)];
  else if (c < 1285)  v = Wh2ab[k * 2 + (c - 1283)];
  else if (c == 1285) v = Wh2tau[k];
  Wcat[idx] = v;
}

__global__ void pack_wicat(const float* __restrict__ Wi2c, const float* __restrict__ Wi2w,
                           const float* __restrict__ Wi2g, const float* __restrict__ Wi2ab,
                           float* __restrict__ Wicat) {
  int idx = blockIdx.x * blockDim.x + threadIdx.x;
  if (idx >= ID * WC) return;
  int k = idx / WC, c = idx % WC;
  float v = 0.0f;
  if (c < 1024)      v = Wi2c[(size_t)k * HD + c];
  else if (c < 1280) v = Wi2w[(size_t)k * AC + (c - 1024)];
  else if (c < 1283) v = Wi2g[k * 3 + (c - 1280)];
  else if (c < 1285) v = Wi2ab[k * 2 + (c - 1283)];
  Wicat[idx] = v;  // tau col = 0 (no emb term in tau)
}

__global__ void addrw_kernel(const float* __restrict__ mem_bias,
                             const float* __restrict__ Wm2w,
                             float* __restrict__ addrW, float* __restrict__ addrWT) {
  int idx = blockIdx.x * blockDim.x + threadIdx.x;
  if (idx >= NS * AC) return;
  int n = idx / AC, m = idx % AC;
  float acc = 0.0f;
  for (int k = 0; k < AA; k++) acc += mem_bias[(size_t)n * AC + k] * Wm2w[(size_t)k * AC + m];
  addrW[(size_t)n * AC + m] = acc;
  addrWT[(size_t)m * NS + n] = acc;
}

__global__ void init_kernel(const float* __restrict__ hid, float* __restrict__ h,
                            float* __restrict__ cc, float* __restrict__ w_sum,
                            int* __restrict__ lastWriter, float* __restrict__ u2w) {
  int idx = blockIdx.x * blockDim.x + threadIdx.x;
  if (idx < BB * HD) { h[idx] = hid[idx]; cc[idx] = 0.0f; }
  if (idx < BB * NS) { w_sum[idx] = 0.0f; lastWriter[idx] = -1; }
  if (idx < BB * AC) { u2w[idx] = 0.0f; }
}

// ---------------- big fp32 GEMM (icat = inp @ Wicat), 64x64 tile -----------
__global__ __launch_bounds__(256) void gemm_big(const float* __restrict__ A,
                                                const float* __restrict__ W,
                                                float* __restrict__ C,
                                                int M, int K, int Nw) {
  __shared__ float sAT[32][68];  // [kk][r], pad 68: 272B stride (16-mult)
  __shared__ float sW[32][68];
  int tx = threadIdx.x & 15, ty = threadIdx.x >> 4;
  int m0 = blockIdx.x * 64, n0 = blockIdx.y * 64;
  float acc[4][4] = {};
  for (int k0 = 0; k0 < K; k0 += 32) {
    for (int i = threadIdx.x; i < 64 * 32; i += 256) {
      int r = i >> 5, kk = i & 31;
      sAT[kk][r] = A[(size_t)(m0 + r) * K + k0 + kk];
    }
    for (int i = threadIdx.x; i < 32 * 64; i += 256) {
      int kk = i >> 6, c = i & 63;
      sW[kk][c] = W[(size_t)(k0 + kk) * Nw + n0 + c];
    }
    __syncthreads();
#pragma unroll
    for (int kk = 0; kk < 32; kk++) {
      float4 a = *(const float4*)&sAT[kk][ty * 4];
      float4 b = *(const float4*)&sW[kk][tx * 4];
      acc[0][0] += a.x * b.x; acc[0][1] += a.x * b.y; acc[0][2] += a.x * b.z; acc[0][3] += a.x * b.w;
      acc[1][0] += a.y * b.x; acc[1][1] += a.y * b.y; acc[1][2] += a.y * b.z; acc[1][3] += a.y * b.w;
      acc[2][0] += a.z * b.x; acc[2][1] += a.z * b.y; acc[2][2] += a.z * b.z; acc[2][3] += a.z * b.w;
      acc[3][0] += a.w * b.x; acc[3][1] += a.w * b.y; acc[3][2] += a.w * b.z; acc[3][3] += a.w * b.w;
    }
    __syncthreads();
  }
#pragma unroll
  for (int i = 0; i < 4; i++) {
    float4 st = make_float4(acc[i][0], acc[i][1], acc[i][2], acc[i][3]);
    *(float4*)&C[(size_t)(m0 + ty * 4 + i) * Nw + n0 + tx * 4] = st;
  }
}

// ---------------- per-step: hcat split-K partials --------------------------
// grid (168, 2): tile = blockIdx.x (mt = tile&3 -> 4x32 rows, nt = tile>>2 -> 42x32 cols),
// part = blockIdx.y (K halves). Output hcp[part][b][WC].
__global__ __launch_bounds__(256) void prep_gemm(const float* __restrict__ h,
                                                 const float* __restrict__ Wcat,
                                                 float* __restrict__ hcp) {
  __shared__ float sAT[64][36];  // [kk][r] KC=64, TM=32, 144B stride (16-mult)
  __shared__ float sW[64][33];
  int tile = blockIdx.x, part = blockIdx.y;
  int m0 = (tile & 3) * 32, n0 = (tile >> 2) * 32;
  int col = threadIdx.x & 31, rg = threadIdx.x >> 5;
  float acc[4] = {};
  int kbase = part * 512;
  for (int k0 = kbase; k0 < kbase + 512; k0 += 64) {
    for (int i = threadIdx.x; i < 32 * 64; i += 256) {
      int r = i >> 6, kk = i & 63;
      sAT[kk][r] = h[(size_t)(m0 + r) * HD + k0 + kk];
    }
    for (int i = threadIdx.x; i < 64 * 32; i += 256) {
      int kk = i >> 5, c = i & 31;
      sW[kk][c] = Wcat[(size_t)(k0 + kk) * WC + n0 + c];
    }
    __syncthreads();
#pragma unroll 8
    for (int kk = 0; kk < 64; kk++) {
      float4 a = *(const float4*)&sAT[kk][rg * 4];
      float w = sW[kk][col];
      acc[0] += a.x * w; acc[1] += a.y * w; acc[2] += a.z * w; acc[3] += a.w * w;
    }
    __syncthreads();
  }
  float* o = hcp + (size_t)part * BB * WC;
#pragma unroll
  for (int j = 0; j < 4; j++)
    o[(size_t)(m0 + rg * 4 + j) * WC + n0 + col] = acc[j];
}

// ---------------- per-step: per-batch chain --------------------------------
__global__ __launch_bounds__(512) void chain_kernel(
    const float* __restrict__ hcp, const float* __restrict__ icat,
    const float* __restrict__ addrW, const float* __restrict__ addrWT,
    const float* __restrict__ atten, const float* __restrict__ mem_bias,
    const float* __restrict__ Wr2g, const float* __restrict__ Wr2ab,
    const float* __restrict__ Wr2c, const float* __restrict__ Wh2m,
    const float* __restrict__ Wm2w, const float* __restrict__ Wu2w,
    const float* __restrict__ b_h2tau,
    float* __restrict__ hbuf, float* __restrict__ ccbuf,
    float* __restrict__ w_sum, float* __restrict__ u2w,
    float* __restrict__ valHist, float* __restrict__ valWHist,
    int* __restrict__ lastWriter, int* __restrict__ writePos,
    float* __restrict__ out, int t) {
  const int b = blockIdx.x, tid = threadIdx.x;
  const int lane = tid & 63, wv = tid >> 6;
  __shared__ float hc[WC];
  __shared__ float att[AC];
  __shared__ float z[NS];
  __shared__ float av[NS];
  __shared__ int   ai[NS];
  __shared__ float rs[AC];
  __shared__ float vhalf[512];
  __shared__ float vs[CCd];
  __shared__ float red[8];
  __shared__ float gdot[5];
  __shared__ float s_fio[3], s_ab[2];
  __shared__ float s_tau, s_zmax;
  __shared__ int   s_ns;

  // stage 0: reduce split-K partials, load atten, build bias in place
  for (int c = tid; c < WC; c += 512)
    hc[c] = hcp[(size_t)b * WC + c] + hcp[(size_t)(BB + b) * WC + c];
  if (tid < AC) att[tid] = atten[tid];
  const float* icrow = icat + (size_t)(t * BB + b) * WC;
  __syncthreads();
  if (tid < AC) hc[COL_W0 + tid] += icrow[COL_W0 + tid] + u2w[(size_t)b * AC + tid];
  __syncthreads();

  // logits pass 1: no-delta version, coalesced addrW^T
  {
    float acc = 0.0f;
    const float* awt = addrWT + tid;
#pragma unroll 4
    for (int k = 0; k < AC; k++)
      acc += tanhf(hc[COL_W0 + k] + awt[(size_t)k * NS]) * att[k];
    z[tid] = acc;
  }
  __syncthreads();
  // correction pass: recompute the <=t written slots with their delta row
  for (int j = wv; j < t; j += 8) {
    int n = writePos[b * LL + j];
    int s = lastWriter[b * NS + n];
    const float* dw = valWHist + ((size_t)b * LL + s) * AC;
    const float* aw = addrW + (size_t)n * AC;
    float p = 0.0f;
    for (int k = lane; k < AC; k += 64)
      p += tanhf(hc[COL_W0 + k] + aw[k] + dw[k]) * att[k];
    for (int off = 32; off; off >>= 1) p += __shfl_down(p, off, 64);
    if (lane == 0) z[n] = p;
  }
  __syncthreads();

  // threefry keys (cheap, per-thread)
  uint32_t k1a, k1b, k2a, k2b;
  threefry2x32(0u, 42u, 0u, 0u, k1a, k1b);
  threefry2x32(0u, 42u, 0u, 1u, k2a, k2b);

  // gumbel + argmax
  {
    uint32_t i = (uint32_t)((t * BB + b) * NS + tid);
    uint32_t o0, o1; threefry2x32(k1a, k1b, 0u, i, o0, o1);
    float v = z[tid] + bits_to_gumbel(o0 ^ o1);
    z[tid] = v; av[tid] = v; ai[tid] = tid;
  }
  __syncthreads();
  for (int off = 256; off; off >>= 1) {
    if (tid < off) {
      float o2 = av[tid + off]; int i2 = ai[tid + off];
      if (o2 > av[tid] || (o2 == av[tid] && i2 < ai[tid])) { av[tid] = o2; ai[tid] = i2; }
    }
    __syncthreads();
  }
  if (tid == 0) {
    float x = hc[COL_TAU] + b_h2tau[0];
    float sp = fmaxf(x, 0.0f) + log1pf(expf(-fabsf(x)));
    s_tau = sp + 1.0f; s_zmax = av[0]; s_ns = ai[0];
  }
  __syncthreads();
  const float tau = s_tau, zmax = s_zmax;
  const int ns = s_ns;
  // softmax denominator
  {
    float e = expf((z[tid] - zmax) / tau);
    for (int off = 32; off; off >>= 1) e += __shfl_down(e, off, 64);
    if (lane == 0) red[wv] = e;
  }
  __syncthreads();
  float D = red[0] + red[1] + red[2] + red[3] + red[4] + red[5] + red[6] + red[7];
  float ystar = 1.0f / D;
  float ws = (1.0f - ystar) + ystar;  // hard - sg(y) + y at argmax; 0 elsewhere

  // r = ws * mem[ns]
  if (tid < AC) {
    int sW_ = lastWriter[b * NS + ns];
    float mv;
    if (tid < AA) mv = mem_bias[(size_t)ns * AC + tid];
    else mv = (sW_ >= 0) ? valHist[((size_t)b * LL + sW_) * CCd + (tid - AA)] : 0.0f;
    rs[tid] = ws * mv;
  }
  __syncthreads();
  // 5 skinny dots: gates (3) + ab (2)
  if (tid < 160) {
    int j = tid >> 5, l = tid & 31;
    float p = 0.0f;
    if (j < 3) { for (int k = l; k < AC; k += 32) p += rs[k] * Wr2g[k * 3 + j]; }
    else { int jj = j - 3; for (int k = l; k < AC; k += 32) p += rs[k] * Wr2ab[k * 2 + jj]; }
    for (int off = 16; off; off >>= 1) p += __shfl_down(p, off, 32);
    if (l == 0) gdot[j] = p;
  }
  __syncthreads();
  if (tid < 3) {
    float x = hc[COL_G0 + tid] + icrow[COL_G0 + tid] + gdot[tid];
    s_fio[tid] = 1.0f / (1.0f + expf(-x));
  } else if (tid < 5) {
    int j = tid - 3;
    float x = hc[COL_AB0 + j] + icrow[COL_AB0 + j] + gdot[tid];
    uint32_t i1 = (uint32_t)(((t * BB + b) * 2 + j) * 2);
    uint32_t o0, o1;
    threefry2x32(k2a, k2b, 0u, i1, o0, o1);     float g1 = bits_to_gumbel(o0 ^ o1);
    threefry2x32(k2a, k2b, 0u, i1 + 1, o0, o1); float g2 = bits_to_gumbel(o0 ^ o1);
    s_ab[j] = (x + g1 - g2) > 0.0f ? 1.0f : 0.0f;
  }
  __syncthreads();
  const float fg = s_fio[0], ig = s_fio[1], og = s_fio[2];
  const float alpha = s_ab[0], beta = s_ab[1];

  // LSTM-ish update, 2 cols/thread
  const int c0 = tid * 2;
  float hn0, hn1;
  {
    float r0 = 0.0f, r1 = 0.0f;
#pragma unroll 4
    for (int k = 0; k < AC; k++) {
      float rk = rs[k];
      float2 w2 = *(const float2*)&Wr2c[(size_t)k * HD + c0];
      r0 += rk * w2.x; r1 += rk * w2.y;
    }
    float2 ic2 = *(const float2*)&icrow[c0];
    float2 cc2 = *(const float2*)&ccbuf[(size_t)b * HD + c0];
    float a0 = beta * hc[c0] + ic2.x + alpha * r0;
    float a1 = beta * hc[c0 + 1] + ic2.y + alpha * r1;
    float cn0 = fg * cc2.x + ig * tanhf(a0);
    float cn1 = fg * cc2.y + ig * tanhf(a1);
    hn0 = og * tanhf(cn0); hn1 = og * tanhf(cn1);
    *(float2*)&ccbuf[(size_t)b * HD + c0] = make_float2(cn0, cn1);
    *(float2*)&hbuf[(size_t)b * HD + c0] = make_float2(hn0, hn1);
    *(float2*)&out[((size_t)t * BB + b) * HD + c0] = make_float2(hn0, hn1);
  }
  hc[c0] = hn0; hc[c0 + 1] = hn1;  // reuse hc[0..1024) as h
  __syncthreads();

  // val = h @ W_h2m  (4-way K split)
  {
    int c = tid & 127, q = tid >> 7;
    const float* wp = Wh2m + c;
    float acc = 0.0f;
    int kb = q * 256;
#pragma unroll 4
    for (int k = kb; k < kb + 256; k++) acc += hc[k] * wp[(size_t)k * CCd];
    vhalf[tid] = acc;
  }
  __syncthreads();
  if (tid < CCd) {
    float val = vhalf[tid] + vhalf[tid + 128] + vhalf[tid + 256] + vhalf[tid + 384];
    vs[tid] = val;
    valHist[((size_t)b * LL + t) * CCd + tid] = val;
  }
  __syncthreads();
  // valW = val @ W_m2w[A:,:]  (2-way C split)
  {
    int m = tid & 255, h2 = tid >> 8;
    float acc = 0.0f;
    int cb = h2 * 64;
#pragma unroll 4
    for (int c = cb; c < cb + 64; c++) acc += vs[c] * Wm2w[(size_t)(AA + c) * AC + m];
    av[tid] = acc;
  }
  __syncthreads();
  if (tid < AC) valWHist[((size_t)b * LL + t) * AC + tid] = av[tid] + av[tid + 256];
  if (tid == 0) {
    int pos = (t * LL < NS) ? (t * LL) : ns;
    writePos[b * LL + t] = pos;
    lastWriter[b * NS + pos] = t;
    w_sum[(size_t)b * NS + ns] += ws;
  }
  __syncthreads();

  // u2w for next step: layernorm(w_sum') @ W_u2w (w_sum' known locally)
  if (t + 1 < LL) {
    float v = w_sum[(size_t)b * NS + tid];  // pre-update value is fine to read
    if (tid == ns) v += ws;                 // apply this step's update locally
    z[tid] = v;
    float s = v;
    for (int off = 32; off; off >>= 1) s += __shfl_down(s, off, 64);
    if (lane == 0) red[wv] = s;
    __syncthreads();
    float mu = (red[0] + red[1] + red[2] + red[3] + red[4] + red[5] + red[6] + red[7]) / (float)NS;
    __syncthreads();  // all read red before rewrite
    float d = (v - mu) * (v - mu);
    for (int off = 32; off; off >>= 1) d += __shfl_down(d, off, 64);
    if (lane == 0) red[wv] = d;
    __syncthreads();
    float var = (red[0] + red[1] + red[2] + red[3] + red[4] + red[5] + red[6] + red[7]) / (float)NS;
    float rsq = rsqrtf(var + 1e-5f);
    z[tid] = (v - mu) * rsq;
    __syncthreads();
    {
      int m = tid & 255, h2 = tid >> 8;
      float acc = 0.0f;
      int kb2 = h2 * 256;
#pragma unroll 4
      for (int k = kb2; k < kb2 + 256; k++) acc += z[k] * Wu2w[(size_t)k * AC + m];
      av[tid] = acc;
    }
    __syncthreads();
    if (tid < AC) u2w[(size_t)b * AC + tid] = av[tid] + av[tid + 256];
  }
}

// ------------------------------ host ---------------------------------------
extern "C" void kernel_launch(void* const* d_in, const int* in_sizes, int n_in,
                              void* d_out, int out_size, void* d_ws, size_t ws_size,
                              hipStream_t stream) {
  const float* inp      = (const float*)d_in[0];
  const float* hid      = (const float*)d_in[1];
  const float* mem_bias = (const float*)d_in[2];
  const float* W_h2w    = (const float*)d_in[3];
  const float* W_i2w    = (const float*)d_in[4];
  const float* W_m2w    = (const float*)d_in[5];
  const float* W_u2w    = (const float*)d_in[6];
  const float* W_h2g    = (const float*)d_in[7];
  const float* W_i2g    = (const float*)d_in[8];
  const float* W_r2g    = (const float*)d_in[9];
  const float* W_h2ab   = (const float*)d_in[10];
  const float* W_i2ab   = (const float*)d_in[11];
  const float* W_r2ab   = (const float*)d_in[12];
  const float* W_h2c    = (const float*)d_in[13];
  const float* W_i2c    = (const float*)d_in[14];
  const float* W_r2c    = (const float*)d_in[15];
  const float* atten    = (const float*)d_in[16];
  const float* W_h2tau  = (const float*)d_in[17];
  const float* b_h2tau  = (const float*)d_in[18];
  const float* W_h2m    = (const float*)d_in[19];
  float* out = (float*)d_out;

  char* base = (char*)d_ws;
  size_t off = 0;
  auto alloc = [&](size_t elems) -> void* {
    void* p = (void*)(base + off);
    off += ((elems * 4 + 255) / 256) * 256;
    return p;
  };
  float* icat     = (float*)alloc((size_t)LL * BB * WC);   // 22 MB
  float* Wicat    = (float*)alloc((size_t)ID * WC);
  float* Wcat     = (float*)alloc((size_t)HD * WC);
  float* addrW    = (float*)alloc((size_t)NS * AC);
  float* addrWT   = (float*)alloc((size_t)NS * AC);
  float* hcp      = (float*)alloc((size_t)2 * BB * WC);
  float* hbuf     = (float*)alloc((size_t)BB * HD);
  float* ccbuf    = (float*)alloc((size_t)BB * HD);
  float* w_sum    = (float*)alloc((size_t)BB * NS);
  float* u2w      = (float*)alloc((size_t)BB * AC);
  float* valHist  = (float*)alloc((size_t)BB * LL * CCd);
  float* valWHist = (float*)alloc((size_t)BB * LL * AC);
  int*   writePos = (int*)alloc((size_t)BB * LL);
  int*   lastWriter = (int*)alloc((size_t)BB * NS);

  hipLaunchKernelGGL(pack_wcat, dim3((HD * WC + 255) / 256), dim3(256), 0, stream,
                     W_h2c, W_h2w, W_h2g, W_h2ab, W_h2tau, Wcat);
  hipLaunchKernelGGL(pack_wicat, dim3((ID * WC + 255) / 256), dim3(256), 0, stream,
                     W_i2c, W_i2w, W_i2g, W_i2ab, Wicat);
  hipLaunchKernelGGL(addrw_kernel, dim3((NS * AC + 255) / 256), dim3(256), 0, stream,
                     mem_bias, W_m2w, addrW, addrWT);
  hipLaunchKernelGGL(init_kernel, dim3((BB * HD + 255) / 256), dim3(256), 0, stream,
                     hid, hbuf, ccbuf, w_sum, lastWriter, u2w);
  hipLaunchKernelGGL(gemm_big, dim3((LL * BB) / 64, WC / 64), dim3(256), 0, stream,
                     inp, Wicat, icat, LL * BB, ID, WC);

  for (int t = 0; t < LL; t++) {
    hipLaunchKernelGGL(prep_gemm, dim3(168, 2), dim3(256), 0, stream, hbuf, Wcat, hcp);
    hipLaunchKernelGGL(chain_kernel, dim3(BB), dim3(512), 0, stream,
                       hcp, icat, addrW, addrWT, atten, mem_bias,
                       W_r2g, W_r2ab, W_r2c, W_h2m, W_m2w, W_u2w, b_h2tau,
                       hbuf, ccbuf, w_sum, u2w, valHist, valWHist,
                       lastWriter, writePos, out, t);
  }
}